// Round 1
// baseline (1205.950 us; speedup 1.0000x reference)
//
#include <hip/hip_runtime.h>
#include <hip/hip_bf16.h>
#include <stdint.h>

typedef __attribute__((ext_vector_type(8))) short s16x8;
typedef __attribute__((ext_vector_type(4))) float f32x4;
#define BF16 __hip_bfloat16

// ---------------- helpers ----------------
__device__ __forceinline__ void gload16(void* lds, const void* g) {
  __builtin_amdgcn_global_load_lds((const __attribute__((address_space(1))) void*)g,
                                   (__attribute__((address_space(3))) void*)lds, 16, 0, 0);
}

__device__ __forceinline__ void inv3(const float* m, float* o) {
  float a00=m[0],a01=m[1],a02=m[2],a10=m[3],a11=m[4],a12=m[5],a20=m[6],a21=m[7],a22=m[8];
  float c00 = a11*a22 - a12*a21;
  float c01 = a12*a20 - a10*a22;
  float c02 = a10*a21 - a11*a20;
  float det = a00*c00 + a01*c01 + a02*c02;
  float id = 1.0f/det;
  o[0]=c00*id; o[1]=(a02*a21-a01*a22)*id; o[2]=(a01*a12-a02*a11)*id;
  o[3]=c01*id; o[4]=(a00*a22-a02*a20)*id; o[5]=(a02*a10-a00*a12)*id;
  o[6]=c02*id; o[7]=(a01*a20-a00*a21)*id; o[8]=(a00*a11-a01*a10)*id;
}

// ---------------- prep: bev_feat (B,192,100,100,8) -> volT[b][x][y][z][c] bf16 ----------------
__global__ __launch_bounds__(192) void k_prep_vol(const float* __restrict__ bev, BF16* __restrict__ volT) {
  int blk = blockIdx.x;               // 0..19999 = b*10000 + x*100 + y
  int b = blk / 10000, xy = blk % 10000;
  int t = threadIdx.x;                // channel c, 0..191
  __shared__ alignas(16) BF16 sm[1536];
  const float* src = bev + (((size_t)b*192 + t)*10000 + xy)*8;
#pragma unroll
  for (int z = 0; z < 8; ++z) sm[z*192 + t] = __float2bfloat16(src[z]);
  __syncthreads();
  BF16* dst = volT + (size_t)blk*1536;
  *reinterpret_cast<s16x8*>(&dst[t*8]) = *reinterpret_cast<const s16x8*>(&sm[t*8]);
}

// ---------------- prep: w1 (256,9600,3,3) -> A1[oc][seg*9600 + dd*192 + c] bf16 ----------------
__global__ __launch_bounds__(256) void k_prep_w1(const float* __restrict__ w1, BF16* __restrict__ A1) {
  unsigned o = blockIdx.x*256u + threadIdx.x;      // < 22,118,400
  unsigned oc = o / 86400u; unsigned r = o % 86400u;
  unsigned seg = r / 9600u; unsigned r2 = r % 9600u;
  unsigned dd = r2 / 192u;  unsigned c  = r2 % 192u;
  unsigned in = (oc*9600u + c*50u + dd)*9u + seg;
  A1[o] = __float2bfloat16(w1[in]);
}

// ---------------- prep: w2 (88,256,3,3) -> w2T[96][seg*256+c] bf16 (rows 88..95 zero) ----------------
__global__ __launch_bounds__(256) void k_prep_w2(const float* __restrict__ w2, BF16* __restrict__ w2T) {
  unsigned o = blockIdx.x*256u + threadIdx.x;      // < 221,184
  unsigned oc = o / 2304u; unsigned r = o % 2304u;
  unsigned seg = r / 256u; unsigned c = r % 256u;
  float v = (oc < 88u) ? w2[(oc*256u + c)*9u + seg] : 0.0f;
  w2T[o] = __float2bfloat16(v);
}

// ---------------- geometry: per (bn, p) sample coordinate in vol space ----------------
__global__ __launch_bounds__(256) void k_geom(const float* __restrict__ s2e, const float* __restrict__ intr,
                       const float* __restrict__ prots, const float* __restrict__ ptrans,
                       const float* __restrict__ bda, float* __restrict__ geom) {
  int tid = blockIdx.x*256 + threadIdx.x;   // < 422400 = 12*35200
  int p = tid % 35200; int bn = tid / 35200;
  int b = bn / 6;
  float PR[9], IN[9], iPR[9], iIN[9], BD[9], SE[12], PT[3];
#pragma unroll
  for (int i = 0; i < 9; ++i) { PR[i] = prots[bn*9+i]; IN[i] = intr[bn*9+i]; BD[i] = bda[b*9+i]; }
#pragma unroll
  for (int i = 0; i < 12; ++i) SE[i] = s2e[bn*16+i];
#pragma unroll
  for (int i = 0; i < 3; ++i) PT[i] = ptrans[bn*3+i];
  inv3(PR, iPR); inv3(IN, iIN);
  float cam[3];
#pragma unroll
  for (int c3 = 0; c3 < 3; ++c3) {
    int f = c3*35200 + p;
    int comp = f % 3; int t1 = f / 3;
    int w = t1 % 44;  int t2 = t1 / 44;
    int h = t2 % 16;  int dd = t2 / 16;
    int hw = h*44 + w;
    float px = 703.0f*(float)(hw >> 4)*(1.0f/43.0f);
    float py = 17.0f*(float)(hw & 15);
    float dv = 1.0f + 44.0f*(float)dd*(1.0f/49.0f);
    float t0 = px - PT[0], t1f = py - PT[1], t2f = dv - PT[2];
    float ux = iPR[0]*t0 + iPR[1]*t1f + iPR[2]*t2f;
    float uy = iPR[3]*t0 + iPR[4]*t1f + iPR[5]*t2f;
    float uz = iPR[6]*t0 + iPR[7]*t1f + iPR[8]*t2f;
    float m0 = ux*uz, m1 = uy*uz, m2 = uz;
    cam[c3] = iIN[comp*3+0]*m0 + iIN[comp*3+1]*m1 + iIN[comp*3+2]*m2;
  }
  float e0 = SE[0]*cam[0] + SE[1]*cam[1] + SE[2]*cam[2] + SE[3];
  float e1 = SE[4]*cam[0] + SE[5]*cam[1] + SE[6]*cam[2] + SE[7];
  float e2 = SE[8]*cam[0] + SE[9]*cam[1] + SE[10]*cam[2] + SE[11];
  float q0 = BD[0]*e0 + BD[1]*e1 + BD[2]*e2;
  float q1 = BD[3]*e0 + BD[4]*e1 + BD[5]*e2;
  float q2 = BD[6]*e0 + BD[7]*e1 + BD[8]*e2;
  float gx = (q0 + 40.0f)*(1.0f/80.0f)*2.0f - 1.0f;
  float gy = (q1 + 40.0f)*(1.0f/80.0f)*2.0f - 1.0f;
  float gz = (q2 + 1.0f)*(1.0f/6.4f)*2.0f - 1.0f;
  float* o = geom + (size_t)tid*3;
  o[0] = (gx + 1.0f)*0.5f*99.0f;
  o[1] = (gy + 1.0f)*0.5f*99.0f;
  o[2] = (gz + 1.0f)*0.5f*7.0f;
}

// ---------------- trilinear sample -> s_p[bn][pixel][dd*192+c] bf16 ----------------
__global__ __launch_bounds__(256) void k_sample(const BF16* __restrict__ volT, const float* __restrict__ geom,
                         BF16* __restrict__ s_p) {
  unsigned tid = blockIdx.x*256u + threadIdx.x;  // < 81,100,800
  unsigned c = tid % 192u; unsigned q = tid / 192u;
  unsigned pix = q % 704u; unsigned q2 = q / 704u;
  unsigned dd = q2 % 50u;  unsigned bn = q2 / 50u;
  unsigned b = bn / 6u;
  const float* g = geom + ((size_t)bn*35200 + dd*704 + pix)*3;
  float X = g[0], Y = g[1], Z = g[2];
  float xf = floorf(X), yf = floorf(Y), zf = floorf(Z);
  int x0 = (int)xf, y0 = (int)yf, z0 = (int)zf;
  float fx = X - xf, fy = Y - yf, fz = Z - zf;
  float acc = 0.0f;
#pragma unroll
  for (int dz = 0; dz < 2; ++dz) {
    int iz = z0 + dz; float wz = dz ? fz : 1.0f - fz;
    bool vz = (iz >= 0) && (iz < 8);
    int cz = min(max(iz, 0), 7);
#pragma unroll
    for (int dy = 0; dy < 2; ++dy) {
      int iy = y0 + dy; float wy = dy ? fy : 1.0f - fy;
      bool vy = vz && (iy >= 0) && (iy < 100);
      int cy = min(max(iy, 0), 99);
#pragma unroll
      for (int dx = 0; dx < 2; ++dx) {
        int ix = x0 + dx; float wx = dx ? fx : 1.0f - fx;
        bool vv = vy && (ix >= 0) && (ix < 100);
        int cx = min(max(ix, 0), 99);
        float wgt = wx*wy*wz;
        if (vv && wgt != 0.0f) {
          size_t a = ((((size_t)b*100 + cx)*100 + cy)*8 + cz)*192 + c;
          acc += wgt * __bfloat162float(volT[a]);
        }
      }
    }
  }
  s_p[((size_t)bn*704 + pix)*9600 + dd*192 + c] = __float2bfloat16(acc);
}

// ---------------- GEMM1: out1_part[ks][bn][oc][pix] = sum_k A1[oc][k] * im2col(s_p) ----------------
// BM=128 BN=128 BK=32, K=86400 split 12x7200. grid = 12(ks) x 6(nt) x 2(mt) x 12(bn) = 1728
__global__ __launch_bounds__(256) void k_gemm1(const BF16* __restrict__ A1, const BF16* __restrict__ s_p,
                        const BF16* __restrict__ zpage, float* __restrict__ part) {
  int gid = blockIdx.x;
  int ks = gid % 12; int t0 = gid / 12;
  int nt = t0 % 6;   t0 /= 6;
  int mt = t0 & 1;   int bn = t0 >> 1;
  int oc0 = mt*128, pix0 = nt*128;
  int tid = threadIdx.x, wv = tid >> 6, lane = tid & 63;
  int wr = wv >> 1, wc = wv & 1;
  __shared__ alignas(16) short lA[4096];
  __shared__ alignas(16) short lB[4096];
  int rsub = lane >> 2, kcol = (lane & 3)*8;
  int lr = lane & 15, kh8 = (lane >> 4)*8;
  int k = ks*7200, kend = k + 7200;
  int arow0 = (wv*2+0)*16 + rsub;
  int arow1 = (wv*2+1)*16 + rsub;
  const BF16* gA0 = A1 + (size_t)(oc0 + arow0)*86400 + k + kcol;
  const BF16* gA1 = A1 + (size_t)(oc0 + arow1)*86400 + k + kcol;
  short* ldsA0 = &lA[(wv*2+0)*512];
  short* ldsA1 = &lA[(wv*2+1)*512];
  short* ldsB0 = &lB[(wv*2+0)*512];
  short* ldsB1 = &lB[(wv*2+1)*512];
  int prow0 = pix0 + (wv*2+0)*16 + rsub;
  int prow1 = pix0 + (wv*2+1)*16 + rsub;
  int ph00 = prow0/44, pw00 = prow0%44;
  int ph10 = prow1/44, pw10 = prow1%44;
  f32x4 acc[4][4] = {};
  while (k < kend) {
    int seg = k / 9600;
    int kloc = k - seg*9600;
    int rem0 = 9600 - kloc, rem1 = kend - k;
    int nsteps = ((rem0 < rem1) ? rem0 : rem1) >> 5;
    int dh = seg/3 - 1, dw = seg%3 - 1;
    const BF16 *gB0, *gB1; int inc0, inc1;
    {
      int ph = ph00 + dh, pw = pw00 + dw;
      bool v = (prow0 < 704) && (ph >= 0) && (ph < 16) && (pw >= 0) && (pw < 44);
      gB0 = v ? s_p + ((size_t)bn*704 + ph*44 + pw)*9600 + kloc + kcol : zpage + kcol;
      inc0 = v ? 32 : 0;
    }
    {
      int ph = ph10 + dh, pw = pw10 + dw;
      bool v = (prow1 < 704) && (ph >= 0) && (ph < 16) && (pw >= 0) && (pw < 44);
      gB1 = v ? s_p + ((size_t)bn*704 + ph*44 + pw)*9600 + kloc + kcol : zpage + kcol;
      inc1 = v ? 32 : 0;
    }
    for (int s = 0; s < nsteps; ++s) {
      __syncthreads();
      gload16(ldsA0, gA0); gload16(ldsA1, gA1);
      gload16(ldsB0, gB0); gload16(ldsB1, gB1);
      __syncthreads();
      s16x8 af[4], bfr[4];
#pragma unroll
      for (int m = 0; m < 4; ++m)
        af[m] = *reinterpret_cast<const s16x8*>(&lA[(wr*64 + m*16 + lr)*32 + kh8]);
#pragma unroll
      for (int n = 0; n < 4; ++n)
        bfr[n] = *reinterpret_cast<const s16x8*>(&lB[(wc*64 + n*16 + lr)*32 + kh8]);
#pragma unroll
      for (int m = 0; m < 4; ++m)
#pragma unroll
        for (int n = 0; n < 4; ++n)
          acc[m][n] = __builtin_amdgcn_mfma_f32_16x16x32_bf16(af[m], bfr[n], acc[m][n], 0, 0, 0);
      gA0 += 32; gA1 += 32; gB0 += inc0; gB1 += inc1;
    }
    k += nsteps*32;
  }
  // epilogue: part[ks][bn][oc][pix]
#pragma unroll
  for (int m = 0; m < 4; ++m) {
    int ocb = oc0 + wr*64 + m*16 + ((lane >> 4) << 2);
#pragma unroll
    for (int n = 0; n < 4; ++n) {
      int px = pix0 + wc*64 + n*16 + lr;
      if (px < 704) {
        float* dst = part + (((size_t)ks*12 + bn)*256 + ocb)*704 + px;
#pragma unroll
        for (int r = 0; r < 4; ++r) dst[(size_t)r*704] = acc[m][n][r];
      }
    }
  }
}

// ---------------- reduce K-splits + bias + relu -> out1p[bn][pixel][oc(256)] bf16 ----------------
__global__ __launch_bounds__(256) void k_reduce1(const float* __restrict__ part, const float* __restrict__ b1,
                          BF16* __restrict__ out1p) {
  int bn = blockIdx.x / 44; int pg = blockIdx.x % 44; int pix0 = pg*16;
  int t = threadIdx.x;
  __shared__ float sm[4096];
  for (int f = t; f < 4096; f += 256) {
    int oc = f >> 4, pl = f & 15;
    float s = 0.0f;
#pragma unroll
    for (int ks = 0; ks < 12; ++ks)
      s += part[(((size_t)ks*12 + bn)*256 + oc)*704 + pix0 + pl];
    s += b1[oc];
    sm[f] = fmaxf(s, 0.0f);
  }
  __syncthreads();
  for (int f = t; f < 4096; f += 256) {
    int pl = f >> 8;      // 0..15
    int oc = f & 255;
    out1p[((size_t)bn*704 + pix0 + pl)*256 + oc] = __float2bfloat16(sm[oc*16 + pl]);
  }
}

// ---------------- GEMM2: conv2 (M=96 padded, K=2304) + bias + relu -> out ----------------
__global__ __launch_bounds__(256) void k_gemm2(const BF16* __restrict__ w2T, const BF16* __restrict__ x1,
                        const BF16* __restrict__ zpage, const float* __restrict__ b2,
                        float* __restrict__ out) {
  int gid = blockIdx.x;                 // 132 = 12*11
  int nt = gid % 11, bn = gid / 11;
  int pix0 = nt*64;
  int tid = threadIdx.x, wv = tid >> 6, lane = tid & 63;
  int wr = wv >> 1, wc = wv & 1;
  __shared__ alignas(16) short lA[3072];
  __shared__ alignas(16) short lB[2048];
  int rsub = lane >> 2, kcol = (lane & 3)*8;
  int lr = lane & 15, kh8 = (lane >> 4)*8;
  int ar0 = wv*16 + rsub;
  int ar1 = (wv+4)*16 + rsub;
  const BF16* gA0 = w2T + (size_t)ar0*2304 + kcol;
  const BF16* gA1 = w2T + (size_t)ar1*2304 + kcol;
  short* lA0 = &lA[wv*512];
  short* lA1 = &lA[(wv+4)*512];
  short* lB0 = &lB[wv*512];
  int prow = pix0 + wv*16 + rsub;       // always < 704
  int ph0 = prow/44, pw0 = prow%44;
  f32x4 acc[3][2] = {};
  for (int seg = 0; seg < 9; ++seg) {
    int dh = seg/3 - 1, dw = seg%3 - 1;
    int ph = ph0 + dh, pw = pw0 + dw;
    bool v = (ph >= 0) && (ph < 16) && (pw >= 0) && (pw < 44);
    const BF16* gB = v ? x1 + ((size_t)bn*704 + ph*44 + pw)*256 + kcol : zpage + kcol;
    int incB = v ? 32 : 0;
#pragma unroll
    for (int s = 0; s < 8; ++s) {
      __syncthreads();
      gload16(lA0, gA0);
      if (wv < 2) gload16(lA1, gA1);
      gload16(lB0, gB);
      __syncthreads();
      s16x8 af[3], bfr[2];
#pragma unroll
      for (int m = 0; m < 3; ++m)
        af[m] = *reinterpret_cast<const s16x8*>(&lA[(wr*48 + m*16 + lr)*32 + kh8]);
#pragma unroll
      for (int n = 0; n < 2; ++n)
        bfr[n] = *reinterpret_cast<const s16x8*>(&lB[(wc*32 + n*16 + lr)*32 + kh8]);
#pragma unroll
      for (int m = 0; m < 3; ++m)
#pragma unroll
        for (int n = 0; n < 2; ++n)
          acc[m][n] = __builtin_amdgcn_mfma_f32_16x16x32_bf16(af[m], bfr[n], acc[m][n], 0, 0, 0);
      gA0 += 32; gA1 += 32; gB += incB;
    }
  }
#pragma unroll
  for (int m = 0; m < 3; ++m) {
    int ocb = wr*48 + m*16 + ((lane >> 4) << 2);
#pragma unroll
    for (int n = 0; n < 2; ++n) {
      int px = pix0 + wc*32 + n*16 + lr;
#pragma unroll
      for (int r = 0; r < 4; ++r) {
        int oc = ocb + r;
        if (oc < 88)
          out[((size_t)bn*88 + oc)*704 + px] = fmaxf(acc[m][n][r] + b2[oc], 0.0f);
      }
    }
  }
}

// ---------------- host launch ----------------
extern "C" void kernel_launch(void* const* d_in, const int* in_sizes, int n_in,
                              void* d_out, int out_size, void* d_ws, size_t ws_size,
                              hipStream_t stream) {
  (void)in_sizes; (void)n_in; (void)out_size;
  const float* bev   = (const float*)d_in[0];
  // d_in[1] = imgs (unused by reference), d_in[3] = ego2globals (unused)
  const float* s2e   = (const float*)d_in[2];
  const float* intr  = (const float*)d_in[4];
  const float* prots = (const float*)d_in[5];
  const float* ptrns = (const float*)d_in[6];
  const float* bda   = (const float*)d_in[7];
  const float* w1    = (const float*)d_in[8];
  const float* b1    = (const float*)d_in[9];
  const float* w2    = (const float*)d_in[10];
  const float* b2    = (const float*)d_in[11];
  float* out = (float*)d_out;

  char* ws = (char*)d_ws;
  size_t off = 0;
  BF16*  volT  = (BF16*)(ws + off);  off += 61440000;     // 2*100*100*8*192 * 2B
  BF16*  A1    = (BF16*)(ws + off);  off += 44236800;     // 256*86400 * 2B
  BF16*  w2T   = (BF16*)(ws + off);  off += 442368;       // 96*2304 * 2B
  float* geom  = (float*)(ws + off); off += 5068800;      // 12*35200*3 * 4B
  BF16*  s_p   = (BF16*)(ws + off);  off += 162201600;    // 12*704*9600 * 2B
  float* part  = (float*)(ws + off); off += 103809024;    // 12*12*256*704 * 4B
  BF16*  out1p = (BF16*)(ws + off);  off += 4325376;      // 12*704*256 * 2B
  BF16*  zpage = (BF16*)(ws + off);  off += 4096;
  if (off > ws_size) return;  // ws too small -> output stays poisoned (diagnostic signature)

  hipMemsetAsync(zpage, 0, 4096, stream);

  k_prep_vol<<<20000, 192, 0, stream>>>(bev, volT);
  k_prep_w1 <<<86400, 256, 0, stream>>>(w1, A1);
  k_prep_w2 <<<864,   256, 0, stream>>>(w2, w2T);
  k_geom    <<<1650,  256, 0, stream>>>(s2e, intr, prots, ptrns, bda, geom);
  k_sample  <<<316800,256, 0, stream>>>(volT, geom, s_p);
  k_gemm1   <<<1728,  256, 0, stream>>>(A1, s_p, zpage, part);
  k_reduce1 <<<528,   256, 0, stream>>>(part, b1, out1p);
  k_gemm2   <<<132,   256, 0, stream>>>(w2T, out1p, zpage, b2, out);
}